// Round 6
// baseline (393.275 us; speedup 1.0000x reference)
//
#include <hip/hip_runtime.h>

typedef __attribute__((ext_vector_type(8))) __bf16 bf16x8;
typedef __attribute__((ext_vector_type(4))) float f32x4;
typedef __attribute__((ext_vector_type(4))) unsigned int u32x4;

__device__ __forceinline__ unsigned short f2bf(float f){
    unsigned int x = __builtin_bit_cast(unsigned int, f);
    x += 0x7FFFu + ((x >> 16) & 1u);
    return (unsigned short)(x >> 16);
}
__device__ __forceinline__ unsigned int pk2(float a, float b){
    return (unsigned int)f2bf(a) | ((unsigned int)f2bf(b) << 16);
}
__device__ __forceinline__ bf16x8 ldfrag(const unsigned short* p){
    u32x4 v = *reinterpret_cast<const u32x4*>(p);
    return __builtin_bit_cast(bf16x8, v);
}
__device__ __forceinline__ bf16x8 ldf32(const float* p){
    f32x4 a = *reinterpret_cast<const f32x4*>(p);
    f32x4 b = *reinterpret_cast<const f32x4*>(p + 4);
    u32x4 r;
    r[0] = pk2(a[0], a[1]); r[1] = pk2(a[2], a[3]);
    r[2] = pk2(b[0], b[1]); r[3] = pk2(b[2], b[3]);
    return __builtin_bit_cast(bf16x8, r);
}
__device__ __forceinline__ f32x4 mfma_bf16(bf16x8 a, bf16x8 b, f32x4 c){
    return __builtin_amdgcn_mfma_f32_16x16x32_bf16(a, b, c, 0, 0, 0);
}

// workspace (shorts): w1f 54*512 = 27648 | w2f 18*512 = 9216 | b1p (float[288])
#define W1F_SH 27648
#define W2F_SH 9216

// ---------------- Kernel 0: weight prep (fragment-major bf16; Q rows pre-scaled) -----
// w1f[f = n*3+ks][lane][8]: permuted row rp = n*16+l15 (rp = c*96+H*32+eh <- orig
// 3*(H*32+eh)+c), elems ks*32+qd*8..; rows rp<96 (c=0, Q) scaled by 1/sqrt(32).
// w2f same for w2. b1p[rp] = b1 permuted (Q part scaled).
__global__ __launch_bounds__(256) void k_prep(const float* __restrict__ w1,
                                              const float* __restrict__ b1,
                                              const float* __restrict__ w2,
                                              unsigned short* __restrict__ w1f,
                                              unsigned short* __restrict__ w2f,
                                              float* __restrict__ b1p)
{
    const float SCALE = 0.17677669529663687f;   // 1/sqrt(32)
    int i = blockIdx.x * 256 + threadIdx.x;
    if (i < 3456){
        int f = i >> 6, lane = i & 63;
        int n = f / 3, ks = f - n * 3;
        int l15 = lane & 15, qd = lane >> 4;
        int rp = n * 16 + l15;
        int c = rp / 96, rem = rp - c * 96;
        float s = (c == 0) ? SCALE : 1.0f;
        const float* src = w1 + (size_t)(3 * rem + c) * 96 + ks * 32 + qd * 8;
        f32x4 v0 = *reinterpret_cast<const f32x4*>(src);
        f32x4 v1 = *reinterpret_cast<const f32x4*>(src + 4);
        u32x4 p;
        p[0] = pk2(v0[0] * s, v0[1] * s); p[1] = pk2(v0[2] * s, v0[3] * s);
        p[2] = pk2(v1[0] * s, v1[1] * s); p[3] = pk2(v1[2] * s, v1[3] * s);
        *reinterpret_cast<u32x4*>(w1f + (size_t)f * 512 + lane * 8) = p;
    } else if (i < 4608){
        int j = i - 3456;
        int f = j >> 6, lane = j & 63;
        int n = f / 3, ks = f - n * 3;
        int l15 = lane & 15, qd = lane >> 4;
        const float* src = w2 + (size_t)(n * 16 + l15) * 96 + ks * 32 + qd * 8;
        f32x4 v0 = *reinterpret_cast<const f32x4*>(src);
        f32x4 v1 = *reinterpret_cast<const f32x4*>(src + 4);
        u32x4 p;
        p[0] = pk2(v0[0], v0[1]); p[1] = pk2(v0[2], v0[3]);
        p[2] = pk2(v1[0], v1[1]); p[3] = pk2(v1[2], v1[3]);
        *reinterpret_cast<u32x4*>(w2f + (size_t)f * 512 + lane * 8) = p;
    } else if (i < 4896){
        int rp = i - 4608;
        int c = rp / 96, rem = rp - c * 96;
        b1p[rp] = b1[3 * rem + c] * ((c == 0) ? SCALE : 1.0f);
    }
}

// ---------------- Kernel 1: fused QKV + attention + projection ----------------------
// LDS: K [3][64][32] swizzled (12288 B) | Vt [3][32][72] (13824 B) = 26112 B.
// Q, P, O all register-resident via swapped-operand MFMA (D rows = 1st operand's
// lane dim) + pair-shuffle repacks. o2 (fp32 [64][100]) aliases K+Vt in phase C.
// Wave w owns q-rows w*16..w*16+15 for all 3 heads.
__global__ __launch_bounds__(256, 5) void k_fused(const float* __restrict__ x,
                                                  const unsigned short* __restrict__ w1f,
                                                  const float* __restrict__ b1p,
                                                  const unsigned short* __restrict__ w2f,
                                                  const float* __restrict__ b2,
                                                  float* __restrict__ out)
{
    __shared__ __align__(16) unsigned short smem[13056];   // 26112 B
    unsigned short* Kr = smem;                              // [H][pos][32] chunk-swizzled
    unsigned short* Vt = smem + 6144;                       // [H][eh][72]
    float* o2 = reinterpret_cast<float*>(smem);             // phase C only

    const int tid = threadIdx.x;
    const int win = blockIdx.x;
    const int b = win >> 6, wy = (win >> 3) & 7, wx = win & 7;
    const int wave = tid >> 6, lane = tid & 63;
    const int l15 = lane & 15, qd = lane >> 4;
    const int s0 = (qd & 1) * 32 + l15;      // pair-shuffle source lanes
    const int s1 = s0 + 16;

    // ---- Phase A: QKV.  Q^T -> registers (swapped operands); K,V -> LDS ----
    bf16x8 bQf[3];
    {
        int pos = wave * 16 + l15;                           // rows >=49 garbage (harmless)
        int iy = pos / 7, ix = pos - iy * 7;
        int h = wy * 7 + iy + 4; if (h >= 56) h -= 56;       // undo roll(-4)
        int w = wx * 7 + ix + 4; if (w >= 56) w -= 56;
        const float* xr = x + ((size_t)b * 3136 + h * 56 + w) * 96;
        bf16x8 aX0 = ldf32(xr + qd * 8);
        bf16x8 aX1 = ldf32(xr + 32 + qd * 8);
        bf16x8 aX2 = ldf32(xr + 64 + qd * 8);

        // group Q (n = 0..5): accQT[e'][pos] = w1q . x^T  (scale pre-folded)
        unsigned int Qw[12];
#pragma unroll
        for (int qt = 0; qt < 6; ++qt){
            const unsigned short* wf = w1f + (size_t)(qt * 3) * 512 + lane * 8;
            f32x4 a = {0.f, 0.f, 0.f, 0.f};
            a = mfma_bf16(ldfrag(wf),        aX0, a);
            a = mfma_bf16(ldfrag(wf + 512),  aX1, a);
            a = mfma_bf16(ldfrag(wf + 1024), aX2, a);
            f32x4 bq = *reinterpret_cast<const f32x4*>(b1p + qt * 16 + qd * 4);
            Qw[qt * 2]     = pk2(a[0] + bq[0], a[1] + bq[1]);
            Qw[qt * 2 + 1] = pk2(a[2] + bq[2], a[3] + bq[3]);
        }
        // repack tile-pairs -> B-frag per head: lane holds Q[q=l15][eh=qd*8..+7]
#pragma unroll
        for (int H = 0; H < 3; ++H){
            u32x4 qw; unsigned int lo, hi;
            lo = (unsigned)__shfl((int)Qw[(2*H)*2],     s0, 64);
            hi = (unsigned)__shfl((int)Qw[(2*H+1)*2],   s0, 64); qw[0] = (qd & 2) ? hi : lo;
            lo = (unsigned)__shfl((int)Qw[(2*H)*2+1],   s0, 64);
            hi = (unsigned)__shfl((int)Qw[(2*H+1)*2+1], s0, 64); qw[1] = (qd & 2) ? hi : lo;
            lo = (unsigned)__shfl((int)Qw[(2*H)*2],     s1, 64);
            hi = (unsigned)__shfl((int)Qw[(2*H+1)*2],   s1, 64); qw[2] = (qd & 2) ? hi : lo;
            lo = (unsigned)__shfl((int)Qw[(2*H)*2+1],   s1, 64);
            hi = (unsigned)__shfl((int)Qw[(2*H+1)*2+1], s1, 64); qw[3] = (qd & 2) ? hi : lo;
            bQf[H] = __builtin_bit_cast(bf16x8, qw);
        }

        // group K (n = 6..11) -> swizzled LDS [H][pos][32]
#pragma unroll
        for (int n = 0; n < 6; ++n){
            const unsigned short* wf = w1f + (size_t)((6 + n) * 3) * 512 + lane * 8;
            f32x4 a = {0.f, 0.f, 0.f, 0.f};
            a = mfma_bf16(aX0, ldfrag(wf),        a);
            a = mfma_bf16(aX1, ldfrag(wf + 512),  a);
            a = mfma_bf16(aX2, ldfrag(wf + 1024), a);
            float bb = b1p[(6 + n) * 16 + l15];
            int H = n >> 1;
            int eh = ((n & 1) << 4) + l15;
            int ch = eh >> 3;
#pragma unroll
            for (int r = 0; r < 4; ++r){
                int p = wave * 16 + qd * 4 + r;
                int chs = ch ^ ((p >> 1) & 3);
                Kr[H * 2048 + p * 32 + chs * 8 + (eh & 7)] = f2bf(a[r] + bb);
            }
        }
        // group V (n = 12..17) -> Vt [H][eh][pos]
#pragma unroll
        for (int n = 0; n < 6; ++n){
            const unsigned short* wf = w1f + (size_t)((12 + n) * 3) * 512 + lane * 8;
            f32x4 a = {0.f, 0.f, 0.f, 0.f};
            a = mfma_bf16(aX0, ldfrag(wf),        a);
            a = mfma_bf16(aX1, ldfrag(wf + 512),  a);
            a = mfma_bf16(aX2, ldfrag(wf + 1024), a);
            float bb = b1p[(12 + n) * 16 + l15];
            int H = n >> 1;
            int eh = ((n & 1) << 4) + l15;
#pragma unroll
            for (int r = 0; r < 4; ++r){
                int p = wave * 16 + qd * 4 + r;
                Vt[(H * 32 + eh) * 72 + p] = f2bf(a[r] + bb);
            }
        }
    }
    __syncthreads();

    // ---- Phase B: S^T = K.Q^T per head; softmax in regs; O^T = V^T.P^T -> regs ----
    const bool rowm = (wy == 7), colm = (wx == 7);
    const float NEGINF = -__builtin_inff();
    unsigned int m49 = 0, m28 = 0, m7 = 0;
#pragma unroll
    for (int tn = 0; tn < 4; ++tn)
#pragma unroll
        for (int r = 0; r < 4; ++r){
            int col = tn * 16 + qd * 4 + r;
            int bit = tn * 4 + r;
            m49 |= (unsigned)(col >= 49) << bit;
            m28 |= (unsigned)(col >= 28) << bit;
            m7  |= (unsigned)((col % 7) >= 4) << bit;
        }
    const int qrow = wave * 16 + l15;
    const bool rhi = (qrow >= 28);
    const bool rc7 = ((qrow % 7) >= 4);
    const int chq = qd ^ ((l15 >> 1) & 3);       // K read-side unswizzle

    unsigned int Ow[12];
#pragma unroll
    for (int H = 0; H < 3; ++H){
        f32x4 S[4];
#pragma unroll
        for (int tn = 0; tn < 4; ++tn){
            bf16x8 aK = ldfrag(Kr + H * 2048 + (tn * 16 + l15) * 32 + chq * 8);
            f32x4 z = {0.f, 0.f, 0.f, 0.f};
            S[tn] = mfma_bf16(aK, bQf[H], z);    // S^T[k=tn*16+qd*4+r][q=l15]
        }
        float mx = NEGINF;
#pragma unroll
        for (int tn = 0; tn < 4; ++tn)
#pragma unroll
            for (int r = 0; r < 4; ++r){
                int bit = tn * 4 + r;
                float v = S[tn][r];              // scale pre-folded into Q
                bool blocked = (((m49 >> bit) & 1u) != 0u)
                    || (rowm && (rhi != (((m28 >> bit) & 1u) != 0u)))
                    || (colm && (rc7 != (((m7 >> bit) & 1u) != 0u)));
                v = blocked ? NEGINF : v;
                S[tn][r] = v;
                mx = fmaxf(mx, v);
            }
        mx = fmaxf(mx, __shfl_xor(mx, 16, 64));
        mx = fmaxf(mx, __shfl_xor(mx, 32, 64));
        float sum = 0.f;
#pragma unroll
        for (int tn = 0; tn < 4; ++tn)
#pragma unroll
            for (int r = 0; r < 4; ++r){
                float e = exp2f((S[tn][r] - mx) * 1.4426950408889634f);
                S[tn][r] = e;
                sum += e;
            }
        sum += __shfl_xor(sum, 16, 64);
        sum += __shfl_xor(sum, 32, 64);
        float inv = 1.f / sum;                   // per-q, lane-local

        unsigned int pkv[8];
#pragma unroll
        for (int tn = 0; tn < 4; ++tn){
            pkv[tn * 2]     = pk2(S[tn][0], S[tn][1]);
            pkv[tn * 2 + 1] = pk2(S[tn][2], S[tn][3]);
        }
        bf16x8 pF[2];                            // B-frag: P[q=l15][k=kt*32+qd*8..]
#pragma unroll
        for (int kt = 0; kt < 2; ++kt){
            u32x4 aw;
#pragma unroll
            for (int w4 = 0; w4 < 4; ++w4){
                int srcl = (w4 < 2) ? s0 : s1;
                unsigned int lo = (unsigned)__shfl((int)pkv[(2 * kt) * 2 + (w4 & 1)], srcl, 64);
                unsigned int hi = (unsigned)__shfl((int)pkv[(2 * kt + 1) * 2 + (w4 & 1)], srcl, 64);
                aw[w4] = (qd & 2) ? hi : lo;
            }
            pF[kt] = __builtin_bit_cast(bf16x8, aw);
        }
        // O^T: rows = eh (qd*4+r per et), cols = q (l15)
#pragma unroll
        for (int et = 0; et < 2; ++et){
            f32x4 o = {0.f, 0.f, 0.f, 0.f};
#pragma unroll
            for (int kt = 0; kt < 2; ++kt){
                bf16x8 aV = ldfrag(Vt + (H * 32 + et * 16 + l15) * 72 + kt * 32 + qd * 8);
                o = mfma_bf16(aV, pF[kt], o);
            }
            Ow[(H * 2 + et) * 2]     = pk2(o[0] * inv, o[1] * inv);
            Ow[(H * 2 + et) * 2 + 1] = pk2(o[2] * inv, o[3] * inv);
        }
    }

    // repack O tile-pairs -> A-frags: lane holds O[row=l15][ch=c*32+qd*8..+7]
    bf16x8 aO[3];
#pragma unroll
    for (int c = 0; c < 3; ++c){
        u32x4 qw; unsigned int lo, hi;
        lo = (unsigned)__shfl((int)Ow[(2*c)*2],     s0, 64);
        hi = (unsigned)__shfl((int)Ow[(2*c+1)*2],   s0, 64); qw[0] = (qd & 2) ? hi : lo;
        lo = (unsigned)__shfl((int)Ow[(2*c)*2+1],   s0, 64);
        hi = (unsigned)__shfl((int)Ow[(2*c+1)*2+1], s0, 64); qw[1] = (qd & 2) ? hi : lo;
        lo = (unsigned)__shfl((int)Ow[(2*c)*2],     s1, 64);
        hi = (unsigned)__shfl((int)Ow[(2*c+1)*2],   s1, 64); qw[2] = (qd & 2) ? hi : lo;
        lo = (unsigned)__shfl((int)Ow[(2*c)*2+1],   s1, 64);
        hi = (unsigned)__shfl((int)Ow[(2*c+1)*2+1], s1, 64); qw[3] = (qd & 2) ? hi : lo;
        aO[c] = __builtin_bit_cast(bf16x8, qw);
    }

    // ---- Phase C: projection (register A-frags, global w2f B-frags) ----
    f32x4 acc2[6];
#pragma unroll
    for (int n = 0; n < 6; ++n){
        const unsigned short* wf = w2f + (size_t)(n * 3) * 512 + lane * 8;
        f32x4 a = {0.f, 0.f, 0.f, 0.f};
        a = mfma_bf16(aO[0], ldfrag(wf),        a);
        a = mfma_bf16(aO[1], ldfrag(wf + 512),  a);
        a = mfma_bf16(aO[2], ldfrag(wf + 1024), a);
        acc2[n] = a;
    }
    __syncthreads();                             // all PV LDS reads done -> reuse as o2

#pragma unroll
    for (int n = 0; n < 6; ++n){
        float bb = b2[n * 16 + l15];
#pragma unroll
        for (int r = 0; r < 4; ++r)
            o2[(wave * 16 + qd * 4 + r) * 100 + n * 16 + l15] = acc2[n][r] + bb;
    }
    __syncthreads();

    // scatter: contiguous 384B fp32 rows to rolled (+3) positions
    {
        int row = tid >> 2, seg = tid & 3;
        if (row < 49){
            int iy = row / 7, ix = row - iy * 7;
            int h = wy * 7 + iy + 3; if (h >= 56) h -= 56;
            int w = wx * 7 + ix + 3; if (w >= 56) w -= 56;
            const float* src = o2 + row * 100 + seg * 24;
            float* dst = out + ((size_t)b * 3136 + h * 56 + w) * 96 + seg * 24;
#pragma unroll
            for (int v = 0; v < 6; ++v){
                f32x4 t4;
#pragma unroll
                for (int j = 0; j < 4; ++j) t4[j] = src[v * 4 + j];
                *reinterpret_cast<f32x4*>(dst + v * 4) = t4;
            }
        }
    }
}

extern "C" void kernel_launch(void* const* d_in, const int* in_sizes, int n_in,
                              void* d_out, int out_size, void* d_ws, size_t ws_size,
                              hipStream_t stream)
{
    const float* x  = (const float*)d_in[0];
    const float* w1 = (const float*)d_in[1];
    const float* b1 = (const float*)d_in[2];
    const float* w2 = (const float*)d_in[3];
    const float* b2 = (const float*)d_in[4];
    float* out = (float*)d_out;

    unsigned short* w1f = (unsigned short*)d_ws;
    unsigned short* w2f = w1f + W1F_SH;
    float* b1p = (float*)(w2f + W2F_SH);

    hipLaunchKernelGGL(k_prep,  dim3(20),   dim3(256), 0, stream, w1, b1, w2, w1f, w2f, b1p);
    hipLaunchKernelGGL(k_fused, dim3(8192), dim3(256), 0, stream, x, w1f, b1p, w2f, b2, out);
}

// Round 7
// 364.640 us; speedup vs baseline: 1.0785x; 1.0785x over previous
//
#include <hip/hip_runtime.h>

typedef __attribute__((ext_vector_type(8))) __bf16 bf16x8;
typedef __attribute__((ext_vector_type(4))) float f32x4;
typedef __attribute__((ext_vector_type(4))) unsigned int u32x4;

__device__ __forceinline__ unsigned short f2bf(float f){
    unsigned int x = __builtin_bit_cast(unsigned int, f);
    x += 0x7FFFu + ((x >> 16) & 1u);
    return (unsigned short)(x >> 16);
}
__device__ __forceinline__ unsigned int pk2(float a, float b){
    return (unsigned int)f2bf(a) | ((unsigned int)f2bf(b) << 16);
}
// HW packed conversion: low16 = bf16(a), high16 = bf16(b), RNE (same as f2bf)
__device__ __forceinline__ unsigned int cvtpk(float a, float b){
    unsigned int r;
    asm("v_cvt_pk_bf16_f32 %0, %1, %2" : "=v"(r) : "v"(a), "v"(b));
    return r;
}
__device__ __forceinline__ unsigned short cvt1(float a){
    return (unsigned short)(cvtpk(a, a) & 0xFFFFu);
}
__device__ __forceinline__ bf16x8 ldfrag(const unsigned short* p){
    u32x4 v = *reinterpret_cast<const u32x4*>(p);
    return __builtin_bit_cast(bf16x8, v);
}
__device__ __forceinline__ bf16x8 ldf32(const float* p){
    f32x4 a = *reinterpret_cast<const f32x4*>(p);
    f32x4 b = *reinterpret_cast<const f32x4*>(p + 4);
    u32x4 r;
    r[0] = cvtpk(a[0], a[1]); r[1] = cvtpk(a[2], a[3]);
    r[2] = cvtpk(b[0], b[1]); r[3] = cvtpk(b[2], b[3]);
    return __builtin_bit_cast(bf16x8, r);
}
__device__ __forceinline__ f32x4 mfma_bf16(bf16x8 a, bf16x8 b, f32x4 c){
    return __builtin_amdgcn_mfma_f32_16x16x32_bf16(a, b, c, 0, 0, 0);
}

// workspace (shorts): w1f 54*512 = 27648 | w2f 18*512 = 9216 | b1p (float[288])
#define W1F_SH 27648
#define W2F_SH 9216

// ---------------- Kernel 0: weight prep (fragment-major bf16; Q rows pre-scaled) -----
__global__ __launch_bounds__(256) void k_prep(const float* __restrict__ w1,
                                              const float* __restrict__ b1,
                                              const float* __restrict__ w2,
                                              unsigned short* __restrict__ w1f,
                                              unsigned short* __restrict__ w2f,
                                              float* __restrict__ b1p)
{
    const float SCALE = 0.17677669529663687f;   // 1/sqrt(32)
    int i = blockIdx.x * 256 + threadIdx.x;
    if (i < 3456){
        int f = i >> 6, lane = i & 63;
        int n = f / 3, ks = f - n * 3;
        int l15 = lane & 15, qd = lane >> 4;
        int rp = n * 16 + l15;
        int c = rp / 96, rem = rp - c * 96;
        float s = (c == 0) ? SCALE : 1.0f;
        const float* src = w1 + (size_t)(3 * rem + c) * 96 + ks * 32 + qd * 8;
        f32x4 v0 = *reinterpret_cast<const f32x4*>(src);
        f32x4 v1 = *reinterpret_cast<const f32x4*>(src + 4);
        u32x4 p;
        p[0] = pk2(v0[0] * s, v0[1] * s); p[1] = pk2(v0[2] * s, v0[3] * s);
        p[2] = pk2(v1[0] * s, v1[1] * s); p[3] = pk2(v1[2] * s, v1[3] * s);
        *reinterpret_cast<u32x4*>(w1f + (size_t)f * 512 + lane * 8) = p;
    } else if (i < 4608){
        int j = i - 3456;
        int f = j >> 6, lane = j & 63;
        int n = f / 3, ks = f - n * 3;
        int l15 = lane & 15, qd = lane >> 4;
        const float* src = w2 + (size_t)(n * 16 + l15) * 96 + ks * 32 + qd * 8;
        f32x4 v0 = *reinterpret_cast<const f32x4*>(src);
        f32x4 v1 = *reinterpret_cast<const f32x4*>(src + 4);
        u32x4 p;
        p[0] = pk2(v0[0], v0[1]); p[1] = pk2(v0[2], v0[3]);
        p[2] = pk2(v1[0], v1[1]); p[3] = pk2(v1[2], v1[3]);
        *reinterpret_cast<u32x4*>(w2f + (size_t)f * 512 + lane * 8) = p;
    } else if (i < 4896){
        int rp = i - 4608;
        int c = rp / 96, rem = rp - c * 96;
        b1p[rp] = b1[3 * rem + c] * ((c == 0) ? SCALE : 1.0f);
    }
}

// ---------------- Kernel 1: fused QKV + attention + projection ----------------------
// LDS: K [3][64][32] swizzled (12288 B) | Vt [3][32][72] (13824 B) = 26112 B.
// Q/P/O register-resident (swapped-operand MFMA + pair-shuffle repacks).
// Phase C stores straight to global (no o2 staging) -> single barrier.
__global__ __launch_bounds__(256, 6) void k_fused(const float* __restrict__ x,
                                                  const unsigned short* __restrict__ w1f,
                                                  const float* __restrict__ b1p,
                                                  const unsigned short* __restrict__ w2f,
                                                  const float* __restrict__ b2,
                                                  float* __restrict__ out)
{
    __shared__ __align__(16) unsigned short smem[13056];   // 26112 B
    unsigned short* Kr = smem;                              // [H][pos][32] chunk-swizzled
    unsigned short* Vt = smem + 6144;                       // [H][eh][72]

    const int tid = threadIdx.x;
    const int win = blockIdx.x;
    const int b = win >> 6, wy = (win >> 3) & 7, wx = win & 7;
    const int wave = tid >> 6, lane = tid & 63;
    const int l15 = lane & 15, qd = lane >> 4;
    const int s0 = (qd & 1) * 32 + l15;      // pair-shuffle source lanes
    const int s1 = s0 + 16;

    // ---- Phase A: QKV.  Q^T -> registers (swapped operands); K,V -> LDS ----
    bf16x8 bQf[3];
    {
        int pos = wave * 16 + l15;                           // rows >=49 garbage (harmless)
        int iy = pos / 7, ix = pos - iy * 7;
        int h = wy * 7 + iy + 4; if (h >= 56) h -= 56;       // undo roll(-4)
        int w = wx * 7 + ix + 4; if (w >= 56) w -= 56;
        const float* xr = x + ((size_t)b * 3136 + h * 56 + w) * 96;
        bf16x8 aX0 = ldf32(xr + qd * 8);
        bf16x8 aX1 = ldf32(xr + 32 + qd * 8);
        bf16x8 aX2 = ldf32(xr + 64 + qd * 8);

        // group Q (n = 0..5): accQT[e'][pos] = w1q . x^T  (scale pre-folded)
        unsigned int Qw[12];
#pragma unroll
        for (int qt = 0; qt < 6; ++qt){
            const unsigned short* wf = w1f + (size_t)(qt * 3) * 512 + lane * 8;
            f32x4 a = {0.f, 0.f, 0.f, 0.f};
            a = mfma_bf16(ldfrag(wf),        aX0, a);
            a = mfma_bf16(ldfrag(wf + 512),  aX1, a);
            a = mfma_bf16(ldfrag(wf + 1024), aX2, a);
            f32x4 bq = *reinterpret_cast<const f32x4*>(b1p + qt * 16 + qd * 4);
            Qw[qt * 2]     = cvtpk(a[0] + bq[0], a[1] + bq[1]);
            Qw[qt * 2 + 1] = cvtpk(a[2] + bq[2], a[3] + bq[3]);
        }
        // repack tile-pairs -> B-frag per head: lane holds Q[q=l15][eh=qd*8..+7]
#pragma unroll
        for (int H = 0; H < 3; ++H){
            u32x4 qw; unsigned int lo, hi;
            lo = (unsigned)__shfl((int)Qw[(2*H)*2],     s0, 64);
            hi = (unsigned)__shfl((int)Qw[(2*H+1)*2],   s0, 64); qw[0] = (qd & 2) ? hi : lo;
            lo = (unsigned)__shfl((int)Qw[(2*H)*2+1],   s0, 64);
            hi = (unsigned)__shfl((int)Qw[(2*H+1)*2+1], s0, 64); qw[1] = (qd & 2) ? hi : lo;
            lo = (unsigned)__shfl((int)Qw[(2*H)*2],     s1, 64);
            hi = (unsigned)__shfl((int)Qw[(2*H+1)*2],   s1, 64); qw[2] = (qd & 2) ? hi : lo;
            lo = (unsigned)__shfl((int)Qw[(2*H)*2+1],   s1, 64);
            hi = (unsigned)__shfl((int)Qw[(2*H+1)*2+1], s1, 64); qw[3] = (qd & 2) ? hi : lo;
            bQf[H] = __builtin_bit_cast(bf16x8, qw);
        }

        // group K (n = 6..11) -> swizzled LDS [H][pos][32]
#pragma unroll
        for (int n = 0; n < 6; ++n){
            const unsigned short* wf = w1f + (size_t)((6 + n) * 3) * 512 + lane * 8;
            f32x4 a = {0.f, 0.f, 0.f, 0.f};
            a = mfma_bf16(aX0, ldfrag(wf),        a);
            a = mfma_bf16(aX1, ldfrag(wf + 512),  a);
            a = mfma_bf16(aX2, ldfrag(wf + 1024), a);
            float bb = b1p[(6 + n) * 16 + l15];
            int H = n >> 1;
            int eh = ((n & 1) << 4) + l15;
            int ch = eh >> 3;
#pragma unroll
            for (int r = 0; r < 4; ++r){
                int p = wave * 16 + qd * 4 + r;
                int chs = ch ^ ((p >> 1) & 3);
                Kr[H * 2048 + p * 32 + chs * 8 + (eh & 7)] = cvt1(a[r] + bb);
            }
        }
        // group V (n = 12..17) -> Vt [H][eh][pos]  (paired b32 writes)
#pragma unroll
        for (int n = 0; n < 6; ++n){
            const unsigned short* wf = w1f + (size_t)((12 + n) * 3) * 512 + lane * 8;
            f32x4 a = {0.f, 0.f, 0.f, 0.f};
            a = mfma_bf16(aX0, ldfrag(wf),        a);
            a = mfma_bf16(aX1, ldfrag(wf + 512),  a);
            a = mfma_bf16(aX2, ldfrag(wf + 1024), a);
            float bb = b1p[(12 + n) * 16 + l15];
            int H = n >> 1;
            int eh = ((n & 1) << 4) + l15;
            int p0 = wave * 16 + qd * 4;
#pragma unroll
            for (int rp = 0; rp < 2; ++rp)
                *reinterpret_cast<unsigned int*>(&Vt[(H * 32 + eh) * 72 + p0 + 2 * rp])
                    = cvtpk(a[2 * rp] + bb, a[2 * rp + 1] + bb);
        }
    }
    __syncthreads();

    // ---- Phase B: S^T = K.Q^T per head; softmax in regs; O^T = V^T.P^T -> regs ----
    const bool rowm = (wy == 7), colm = (wx == 7);
    const float NEGINF = -__builtin_inff();
    // closed-form col-mask tables (depend only on qd); bit = tn*4+r, col = tn*16+qd*4+r
    const unsigned int m49 = (qd == 0) ? 0xE000u : 0xF000u;          // col >= 49
    const unsigned int m28 = (qd == 3) ? 0xFFF0u : 0xFF00u;          // col >= 28
    const unsigned int m7  = (qd & 2) ? ((qd & 1) ? 0x7C03u : 0x03E8u)
                                      : ((qd & 1) ? 0xE817u : 0x17C0u);  // (col%7) >= 4
    const int qrow = wave * 16 + l15;
    const bool rhi = (qrow >= 28);
    const bool rc7 = ((qrow % 7) >= 4);
    const int chq = qd ^ ((l15 >> 1) & 3);       // K read-side unswizzle

    unsigned int Ow[12];
#pragma unroll
    for (int H = 0; H < 3; ++H){
        f32x4 S[4];
#pragma unroll
        for (int tn = 0; tn < 4; ++tn){
            bf16x8 aK = ldfrag(Kr + H * 2048 + (tn * 16 + l15) * 32 + chq * 8);
            f32x4 z = {0.f, 0.f, 0.f, 0.f};
            S[tn] = mfma_bf16(aK, bQf[H], z);    // S^T[k=tn*16+qd*4+r][q=l15]
        }
        float mx = NEGINF;
#pragma unroll
        for (int tn = 0; tn < 4; ++tn)
#pragma unroll
            for (int r = 0; r < 4; ++r){
                int bit = tn * 4 + r;
                float v = S[tn][r];              // scale pre-folded into Q
                bool blocked = (((m49 >> bit) & 1u) != 0u)
                    || (rowm && (rhi != (((m28 >> bit) & 1u) != 0u)))
                    || (colm && (rc7 != (((m7 >> bit) & 1u) != 0u)));
                v = blocked ? NEGINF : v;
                S[tn][r] = v;
                mx = fmaxf(mx, v);
            }
        mx = fmaxf(mx, __shfl_xor(mx, 16, 64));
        mx = fmaxf(mx, __shfl_xor(mx, 32, 64));
        float sum = 0.f;
#pragma unroll
        for (int tn = 0; tn < 4; ++tn)
#pragma unroll
            for (int r = 0; r < 4; ++r){
                float e = exp2f((S[tn][r] - mx) * 1.4426950408889634f);
                S[tn][r] = e;
                sum += e;
            }
        sum += __shfl_xor(sum, 16, 64);
        sum += __shfl_xor(sum, 32, 64);
        float inv = 1.f / sum;                   // per-q, lane-local

        unsigned int pkv[8];
#pragma unroll
        for (int tn = 0; tn < 4; ++tn){
            pkv[tn * 2]     = cvtpk(S[tn][0], S[tn][1]);
            pkv[tn * 2 + 1] = cvtpk(S[tn][2], S[tn][3]);
        }
        bf16x8 pF[2];                            // B-frag: P[q=l15][k=kt*32+qd*8..]
#pragma unroll
        for (int kt = 0; kt < 2; ++kt){
            u32x4 aw;
#pragma unroll
            for (int w4 = 0; w4 < 4; ++w4){
                int srcl = (w4 < 2) ? s0 : s1;
                unsigned int lo = (unsigned)__shfl((int)pkv[(2 * kt) * 2 + (w4 & 1)], srcl, 64);
                unsigned int hi = (unsigned)__shfl((int)pkv[(2 * kt + 1) * 2 + (w4 & 1)], srcl, 64);
                aw[w4] = (qd & 2) ? hi : lo;
            }
            pF[kt] = __builtin_bit_cast(bf16x8, aw);
        }
        // O^T: rows = eh (qd*4+r per et), cols = q (l15)
#pragma unroll
        for (int et = 0; et < 2; ++et){
            f32x4 o = {0.f, 0.f, 0.f, 0.f};
#pragma unroll
            for (int kt = 0; kt < 2; ++kt){
                bf16x8 aV = ldfrag(Vt + (H * 32 + et * 16 + l15) * 72 + kt * 32 + qd * 8);
                o = mfma_bf16(aV, pF[kt], o);
            }
            Ow[(H * 2 + et) * 2]     = cvtpk(o[0] * inv, o[1] * inv);
            Ow[(H * 2 + et) * 2 + 1] = cvtpk(o[2] * inv, o[3] * inv);
        }
    }

    // repack O tile-pairs -> A-frags: lane holds O[row=l15][ch=c*32+qd*8..+7]
    bf16x8 aO[3];
#pragma unroll
    for (int c = 0; c < 3; ++c){
        u32x4 qw; unsigned int lo, hi;
        lo = (unsigned)__shfl((int)Ow[(2*c)*2],     s0, 64);
        hi = (unsigned)__shfl((int)Ow[(2*c+1)*2],   s0, 64); qw[0] = (qd & 2) ? hi : lo;
        lo = (unsigned)__shfl((int)Ow[(2*c)*2+1],   s0, 64);
        hi = (unsigned)__shfl((int)Ow[(2*c+1)*2+1], s0, 64); qw[1] = (qd & 2) ? hi : lo;
        lo = (unsigned)__shfl((int)Ow[(2*c)*2],     s1, 64);
        hi = (unsigned)__shfl((int)Ow[(2*c+1)*2],   s1, 64); qw[2] = (qd & 2) ? hi : lo;
        lo = (unsigned)__shfl((int)Ow[(2*c)*2+1],   s1, 64);
        hi = (unsigned)__shfl((int)Ow[(2*c+1)*2+1], s1, 64); qw[3] = (qd & 2) ? hi : lo;
        aO[c] = __builtin_bit_cast(bf16x8, qw);
    }

    // ---- Phase C: projection; direct predicated global stores (no LDS staging) ----
    f32x4 acc2[6];
#pragma unroll
    for (int n = 0; n < 6; ++n){
        const unsigned short* wf = w2f + (size_t)(n * 3) * 512 + lane * 8;
        f32x4 a = {0.f, 0.f, 0.f, 0.f};
        a = mfma_bf16(aO[0], ldfrag(wf),        a);
        a = mfma_bf16(aO[1], ldfrag(wf + 512),  a);
        a = mfma_bf16(aO[2], ldfrag(wf + 1024), a);
        acc2[n] = a;
    }
    float bb2[6];
#pragma unroll
    for (int n = 0; n < 6; ++n) bb2[n] = b2[n * 16 + l15];

#pragma unroll
    for (int r = 0; r < 4; ++r){
        int row = wave * 16 + qd * 4 + r;
        int iy = row / 7, ix = row - iy * 7;
        int h = wy * 7 + iy + 3; if (h >= 56) h -= 56;   // roll +3
        int w = wx * 7 + ix + 3; if (w >= 56) w -= 56;
        float* dst = out + ((size_t)b * 3136 + h * 56 + w) * 96 + l15;
        if (row < 49){
#pragma unroll
            for (int n = 0; n < 6; ++n)
                dst[n * 16] = acc2[n][r] + bb2[n];
        }
    }
}

extern "C" void kernel_launch(void* const* d_in, const int* in_sizes, int n_in,
                              void* d_out, int out_size, void* d_ws, size_t ws_size,
                              hipStream_t stream)
{
    const float* x  = (const float*)d_in[0];
    const float* w1 = (const float*)d_in[1];
    const float* b1 = (const float*)d_in[2];
    const float* w2 = (const float*)d_in[3];
    const float* b2 = (const float*)d_in[4];
    float* out = (float*)d_out;

    unsigned short* w1f = (unsigned short*)d_ws;
    unsigned short* w2f = w1f + W1F_SH;
    float* b1p = (float*)(w2f + W2F_SH);

    hipLaunchKernelGGL(k_prep,  dim3(20),   dim3(256), 0, stream, w1, b1, w2, w1f, w2f, b1p);
    hipLaunchKernelGGL(k_fused, dim3(8192), dim3(256), 0, stream, x, w1f, b1p, w2f, b2, out);
}